// Round 5
// baseline (106.471 us; speedup 1.0000x reference)
//
#include <hip/hip_runtime.h>
#include <float.h>

#define P_TOTAL 8192
#define F_TOTAL 2048
#define TPB     256                  // 4 waves: 2 points x 2 interleaved group sets
#define NGROUP  32                   // 64-tri groups after spatial sort
#define GPW     16                   // groups per wave
#define NCHUNK  4                    // 4 rounds (groups) per chunk
#define NCELL   64                   // 4x4x4 Morton cells

// Correctly-rounded f32 division via shared refined reciprocal (Markstein).
// R8-verified bit-exact on HW.
__device__ __forceinline__ float refine_rcp(float D) {
#pragma clang fp contract(off)
    float r0 = __builtin_amdgcn_rcpf(D);
    float e1 = __builtin_fmaf(-D, r0, 1.0f);
    return __builtin_fmaf(e1, r0, r0);
}
__device__ __forceinline__ float div_rn(float num, float D, float r) {
#pragma clang fp contract(off)
    float q0 = num * r;
    float e  = __builtin_fmaf(-D, q0, num);
    return __builtin_fmaf(e, r, q0);
}

// Scalar region-select, bit-exact vs numpy (proven R2..R17).
__device__ __forceinline__ void region_select(
    float d1, float d2, float d3, float d4, float d5, float d6,
    float va, float vb, float vc, float d43, float d56,
    float g1, float g2, float g3, float g4,
    float& bu, float& bv, float& bw)
{
#pragma clang fp contract(off)
    float G1 = fmaxf(g1, 1e-12f);
    float G2 = fmaxf(g2, 1e-12f);
    float G3 = fmaxf(g3, 1e-12f);
    float G4 = fmaxf(g4, 1e-12f);

    bool cA  = (d1 <= 0.f) & (d2 <= 0.f);
    bool cB  = (d3 >= 0.f) & (d4 <= d3);
    bool cAB = (vc <= 0.f) & (d1 >= 0.f) & (d3 <= 0.f);
    bool cC  = (d6 >= 0.f) & (d5 <= d6);
    bool cAC = (vb <= 0.f) & (d2 >= 0.f) & (d6 <= 0.f);
    bool cBC = (va <= 0.f) & (d43 >= 0.f) & (d56 >= 0.f);

    float nv = cA ? 0.f : cB ? 1.f : cAB ? d1 : cC ? 0.f
             : cAC ? 0.f : cBC ? d43 : vb;
    float nw = cA ? 0.f : cB ? 0.f : cAB ? 0.f : cC ? 1.f
             : cAC ? d2 : cBC ? d43 : vc;
    float D  = cA ? 1.f : cB ? 1.f : cAB ? G1 : cC ? 1.f
             : cAC ? G2 : cBC ? G3 : G4;
    bool fBC = cBC && !(cA || cB || cAB || cC || cAC);

    float r   = refine_rcp(D);
    float qv  = div_rn(nv, D, r);
    float bww = div_rn(nw, D, r);
    float bvv = fBC ? (1.0f - qv) : qv;
    bv = bvv; bw = bww;
    bu = (1.0f - bvv) - bww;
}

// Exact point-vs-tri, R8's verbatim op order (bit-exact vs numpy).
__device__ __forceinline__ float eval_exact(
    float px, float py, float pz, float4 q0, float4 q1, float4 q2)
{
#pragma clang fp contract(off)
    float ax = q0.x, ay = q0.y, az = q0.z;
    float bx = q0.w, by = q1.x, bz = q1.y;
    float cx = q1.z, cy = q1.w, cz = q2.x;

    float abx = bx - ax, aby = by - ay, abz = bz - az;
    float acx = cx - ax, acy = cy - ay, acz = cz - az;
    float apx = px - ax, apy = py - ay, apz = pz - az;
    float d1 = (abx * apx + aby * apy) + abz * apz;
    float d2 = (acx * apx + acy * apy) + acz * apz;
    float bpx = px - bx, bpy = py - by, bpz = pz - bz;
    float d3 = (abx * bpx + aby * bpy) + abz * bpz;
    float d4 = (acx * bpx + acy * bpy) + acz * bpz;
    float cpx = px - cx, cpy = py - cy, cpz = pz - cz;
    float d5 = (abx * cpx + aby * cpy) + abz * cpz;
    float d6 = (acx * cpx + acy * cpy) + acz * cpz;

    float vc = d1 * d4 - d3 * d2;
    float vb = d5 * d2 - d1 * d6;
    float va = d3 * d6 - d5 * d4;
    float d43 = d4 - d3, d56 = d5 - d6;
    float g1 = d1 - d3, g2 = d2 - d6, g3 = d43 + d56, g4 = (va + vb) + vc;

    float bu, bv, bw;
    region_select(d1, d2, d3, d4, d5, d6, va, vb, vc, d43, d56,
                  g1, g2, g3, g4, bu, bv, bw);

    float cpx2 = (ax * bu + bx * bv) + cx * bw;
    float cpy2 = (ay * bu + by * bv) + cy * bw;
    float cpz2 = (az * bu + bz * bv) + cz * bw;
    float dx = px - cpx2, dy = py - cpy2, dz = pz - cpz2;
    return (dx * dx + dy * dy) + dz * dz;
}

// R5 PREP: single-block counting sort of the 2048 tris by Morton code of
// centroid (4x4x4 grid over [-3,3]^3), writing spatially-sorted pre_n /
// pre_v / pre_a (orig tri idx stowed in pre_v[3t+2].y), then one bounding
// sphere per 64-tri sorted group (radius has +1e-4 rel slack; all sphere
// fp error is inside main's 2% prune margin). Scatter order within a cell
// is nondeterministic (LDS atomics) but output is order-independent: evals
// are bit-exact and argmin ties resolve by ORIGINAL index (see FLUSH).
__global__ __launch_bounds__(1024) void msdf_prep(
    const float* __restrict__ verts, const int* __restrict__ faces,
    float4* __restrict__ pre_n, float4* __restrict__ pre_v,
    float4* __restrict__ pre_a, float4* __restrict__ spheres)
{
    __shared__ int s_cur[NCELL];
    __shared__ int s_base[NCELL];
    const int tid = threadIdx.x;
    if (tid < NCELL) s_cur[tid] = 0;
    __syncthreads();

    float vtx[2][9];
    float4 pl[2];
    int   cl[2];
    #pragma unroll
    for (int i = 0; i < 2; ++i) {
        int t = tid + i * 1024;
        int i0 = faces[3 * t + 0], i1 = faces[3 * t + 1], i2 = faces[3 * t + 2];
        float ax = verts[3 * i0], ay = verts[3 * i0 + 1], az = verts[3 * i0 + 2];
        float bx = verts[3 * i1], by = verts[3 * i1 + 1], bz = verts[3 * i1 + 2];
        float cx = verts[3 * i2], cy = verts[3 * i2 + 1], cz = verts[3 * i2 + 2];
        float e1x = bx - ax, e1y = by - ay, e1z = bz - az;
        float e2x = cx - ax, e2y = cy - ay, e2z = cz - az;
        float nx = e1y * e2z - e1z * e2y;
        float ny = e1z * e2x - e1x * e2z;
        float nz = e1x * e2y - e1y * e2x;
        float nn = (nx * nx + ny * ny) + nz * nz;
        float inv = (nn > 1e-30f) ? (1.0f / sqrtf(nn)) : 0.0f;  // degen -> lb=0
        nx *= inv; ny *= inv; nz *= inv;
        pl[i] = make_float4(nx, ny, nz, (nx * ax + ny * ay) + nz * az);
        vtx[i][0] = ax; vtx[i][1] = ay; vtx[i][2] = az;
        vtx[i][3] = bx; vtx[i][4] = by; vtx[i][5] = bz;
        vtx[i][6] = cx; vtx[i][7] = cy; vtx[i][8] = cz;
        float cxm = (ax + bx + cx) * (1.0f / 3.0f);
        float cym = (ay + by + cy) * (1.0f / 3.0f);
        float czm = (az + bz + cz) * (1.0f / 3.0f);
        int ix = min(max((int)floorf((cxm + 3.0f) * (4.0f / 6.0f)), 0), 3);
        int iy = min(max((int)floorf((cym + 3.0f) * (4.0f / 6.0f)), 0), 3);
        int iz = min(max((int)floorf((czm + 3.0f) * (4.0f / 6.0f)), 0), 3);
        cl[i] = (ix & 1) | ((iy & 1) << 1) | ((iz & 1) << 2)
              | ((ix >> 1) << 3) | ((iy >> 1) << 4) | ((iz >> 1) << 5);
        atomicAdd(&s_cur[cl[i]], 1);
    }
    __syncthreads();
    if (tid == 0) {
        int a = 0;
        for (int i = 0; i < NCELL; ++i) { int c = s_cur[i]; s_base[i] = a; a += c; }
    }
    __syncthreads();
    if (tid < NCELL) s_cur[tid] = s_base[tid];
    __syncthreads();
    #pragma unroll
    for (int i = 0; i < 2; ++i) {
        int t = tid + i * 1024;
        int pos = atomicAdd(&s_cur[cl[i]], 1);
        pre_n[pos] = pl[i];
        pre_v[3 * pos + 0] = make_float4(vtx[i][0], vtx[i][1], vtx[i][2], vtx[i][3]);
        pre_v[3 * pos + 1] = make_float4(vtx[i][4], vtx[i][5], vtx[i][6], vtx[i][7]);
        pre_v[3 * pos + 2] = make_float4(vtx[i][8], __int_as_float(t), 0.f, 0.f);
        pre_a[pos] = make_float4(vtx[i][0], vtx[i][1], vtx[i][2], 0.f);
    }
    __threadfence();
    __syncthreads();

    // Group bounding spheres: wave v handles groups v and v+16.
    const int wv = tid >> 6, lane = tid & 63;
    for (int g = wv; g < NGROUP; g += 16) {
        int t = g * 64 + lane;
        float4 q0 = pre_v[3 * t + 0];
        float4 q1 = pre_v[3 * t + 1];
        float4 q2 = pre_v[3 * t + 2];
        float ax2 = q0.x, ay2 = q0.y, az2 = q0.z;
        float bx2 = q0.w, by2 = q1.x, bz2 = q1.y;
        float cx2 = q1.z, cy2 = q1.w, cz2 = q2.x;
        float sx = (ax2 + bx2 + cx2) * (1.0f / 3.0f);
        float sy = (ay2 + by2 + cy2) * (1.0f / 3.0f);
        float sz = (az2 + bz2 + cz2) * (1.0f / 3.0f);
        #pragma unroll
        for (int off = 32; off; off >>= 1) {
            sx += __shfl_xor(sx, off, 64);
            sy += __shfl_xor(sy, off, 64);
            sz += __shfl_xor(sz, off, 64);
        }
        float ccx = sx * (1.0f / 64.0f), ccy = sy * (1.0f / 64.0f), ccz = sz * (1.0f / 64.0f);
        float dax = ax2 - ccx, day = ay2 - ccy, daz = az2 - ccz;
        float dbx = bx2 - ccx, dby = by2 - ccy, dbz = bz2 - ccz;
        float dcx = cx2 - ccx, dcy = cy2 - ccy, dcz = cz2 - ccz;
        float r2 = fmaxf(fmaxf((dax*dax+day*day)+daz*daz,
                               (dbx*dbx+dby*dby)+dbz*dbz),
                               (dcx*dcx+dcy*dcy)+dcz*dcz);
        #pragma unroll
        for (int off = 32; off; off >>= 1)
            r2 = fmaxf(r2, __shfl_xor(r2, off, 64));
        if (lane == 0)
            spheres[g] = make_float4(ccx, ccy, ccz, sqrtf(r2) * 1.0001f + 1e-6f);
    }
}

// One eval body over `take` queued survivors (dup-head lanes idempotent).
// Accumulates per-lane ubloc; caller reduces once per chunk (R17 win).
// Sorted order != original order, so exact-d2 ties (common: two tris
// sharing the closest vertex) need an explicit ORIGINAL-index tie-break
// to preserve the reference's first-occurrence argmin.
#define FLUSH_BODY(take) do {                                             \
    int j = (lane < (take)) ? lane : 0;                                   \
    int t = slist[w][(h + j) & 511];                                      \
    float4 q0 = pre_v[3 * t + 0];                                         \
    float4 q1 = pre_v[3 * t + 1];                                         \
    float4 q2 = pre_v[3 * t + 2];                                         \
    float d2v = eval_exact(px, py, pz, q0, q1, q2);                       \
    int oi = __float_as_int(q2.y);                                        \
    unsigned int bits = __float_as_uint(d2v);                             \
    if (bits < best_bits || (bits == best_bits && oi < best_idx)) {       \
        best_bits = bits; best_idx = oi;                                  \
    }                                                                     \
    ubloc = fminf(ubloc, d2v);                                            \
    h += (take); pend -= (take);                                          \
} while (0)

// Branch-and-bound, 2 WAVES PER POINT over SPATIALLY SORTED groups.
// R5 CHANGE: group-sphere pruning. Lanes 0..15 hold the wave's 16 group
// sphere lower-bounds (groups interleaved round-robin between the two
// waves for balance); one ballot per chunk gives the active-round mask;
// inactive 64-tri rounds are skipped wave-uniformly. Sphere lb kills the
// far-but-nearly-coplanar tris the plane lb can't -> fewer plane rounds
// AND fewer exact evals. Seed ub: 256 A-verts strided x8 across ALL
// groups (global coverage). Argmin tri's group always active
// (lb <= d2 <= ub < ubm); evals bit-exact; 2% margin covers all fp error.
// R3 LESSON: waves stay independent until the final merge (no mid-scan
// __syncthreads). R2 LESSON: no contended global atomics/fences (~150us).
__global__ __launch_bounds__(TPB) void msdf_main(
    const float4* __restrict__ pre_n, const float4* __restrict__ pre_v,
    const float4* __restrict__ pre_a, const float4* __restrict__ spheres,
    const float* __restrict__ points, float* __restrict__ out)
{
    __shared__ int slist[4][512];                  // per-wave FIFO (8 KB)
    __shared__ unsigned long long keys[4];
    const int tid  = threadIdx.x;
    const int lane = tid & 63;
    const int w    = tid >> 6;
    const int p    = blockIdx.x * 2 + (w >> 1);    // 2 points per block
    const int par  = w & 1;                        // group parity for this wave

    const float px = points[3 * p], py = points[3 * p + 1], pz = points[3 * p + 2];

    // Sphere lower bound for this wave's 16 groups (lane k <-> group 2k+par).
    float lb2;
    {
        float4 s = spheres[2 * (lane & 15) + par];
        float dx = px - s.x, dy = py - s.y, dz = pz - s.z;
        float dc = sqrtf((dx * dx + dy * dy) + dz * dz);
        float lb = fmaxf(dc - s.w, 0.f);
        lb2 = lb * lb;
    }

    // ub seed: 256 A-verts strided x8 -> covers all 32 groups.
    float u = FLT_MAX;
    #pragma unroll
    for (int s = 0; s < 4; ++s) {
        float4 q = pre_a[8 * (s * 64 + lane)];
        float dx = px - q.x, dy = py - q.y, dz = pz - q.z;
        u = fminf(u, (dx * dx + dy * dy) + dz * dz);
    }
    #pragma unroll
    for (int off = 32; off; off >>= 1)
        u = fminf(u, __shfl_xor(u, off, 64));
    float ub = u;

    unsigned int best_bits = 0xFFFFFFFFu;
    int best_idx = 0x7FFFFFFF;
    int pend = 0, h = 0;

    for (int c = 0; c < NCHUNK; ++c) {
        const float ubm = ub * 1.02f + 1e-18f;
        unsigned long long bm = __ballot((lane < GPW) && (lb2 <= ubm));
        #pragma unroll
        for (int k = 0; k < 4; ++k) {
            if ((bm >> (4 * c + k)) & 1ull) {
                int g = 2 * (4 * c + k) + par;
                int t = g * 64 + lane;
                float4 n = pre_n[t];
                float lv = ((n.x * px + n.y * py) + n.z * pz) - n.w;
                bool pred = (lv * lv <= ubm);
                unsigned long long m = __ballot(pred);
                if (pred) {
                    int off = (int)__popcll(m & ((1ull << lane) - 1ull));
                    slist[w][(h + pend + off) & 511] = t;
                }
                pend += (int)__popcll(m);
            }
        }

        bool drain = (c == 0) || (c == NCHUNK - 1);
        if (pend >= 64 || (drain && pend > 0)) {
            float ubloc = FLT_MAX;
            while (pend >= 64) FLUSH_BODY(64);
            if (drain && pend > 0) FLUSH_BODY(pend);
            #pragma unroll
            for (int off = 32; off; off >>= 1)
                ubloc = fminf(ubloc, __shfl_xor(ubloc, off, 64));
            ub = fminf(ub, ubloc);
        }
    }

    // in-wave packed min, then cross-wave merge of the two waves' sets
    unsigned long long key =
        ((unsigned long long)best_bits << 32) | (unsigned int)best_idx;
    #pragma unroll
    for (int off = 32; off > 0; off >>= 1) {
        unsigned int hi = (unsigned int)(key >> 32);
        unsigned int lo = (unsigned int)(key & 0xFFFFFFFFu);
        unsigned int ohi = __shfl_down(hi, off, 64);
        unsigned int olo = __shfl_down(lo, off, 64);
        unsigned long long ok = ((unsigned long long)ohi << 32) | olo;
        key = (ok < key) ? ok : key;
    }
    if (lane == 0) keys[w] = key;
    __syncthreads();
    if (tid < 2) {                                  // tid: point blockIdx*2+tid
        unsigned long long k0 = keys[2 * tid];
        unsigned long long k1 = keys[2 * tid + 1];
        unsigned long long km = (k1 < k0) ? k1 : k0;
        int pp = blockIdx.x * 2 + tid;
        out[1 + pp]           = __uint_as_float((unsigned int)(km >> 32));
        out[1 + P_TOTAL + pp] = (float)(unsigned int)(km & 0xFFFFFFFFu);
    }
}

// Deterministic single-block loss reduction: out[0] = sum(dist) * 1000/P.
// No atomics (R5 lesson; re-confirmed catastrophically in R2 — contended
// device atomics + fences cost ~150 us).
__global__ __launch_bounds__(256) void msdf_loss(float* __restrict__ out)
{
    __shared__ float wsum[4];
    float s = 0.f;
    for (int k = 0; k < P_TOTAL / 256; ++k)
        s += out[1 + k * 256 + threadIdx.x];
    #pragma unroll
    for (int off = 32; off > 0; off >>= 1) s += __shfl_down(s, off, 64);
    int lane = threadIdx.x & 63, w = threadIdx.x >> 6;
    if (lane == 0) wsum[w] = s;
    __syncthreads();
    if (threadIdx.x == 0) {
        float tot = ((wsum[0] + wsum[1]) + wsum[2]) + wsum[3];
        out[0] = tot * (1000.0f / (float)P_TOTAL);
    }
}

extern "C" void kernel_launch(void* const* d_in, const int* in_sizes, int n_in,
                              void* d_out, int out_size, void* d_ws, size_t ws_size,
                              hipStream_t stream) {
    const float* verts  = (const float*)d_in[0];
    const int*   faces  = (const int*)d_in[1];
    const float* points = (const float*)d_in[2];
    float* out = (float*)d_out;
    float4* pre_n   = (float4*)d_ws;                                    // 32 KB
    float4* pre_v   = (float4*)((char*)d_ws + F_TOTAL * 16);            // 96 KB
    float4* pre_a   = (float4*)((char*)d_ws + F_TOTAL * 16 * 4);        // 32 KB
    float4* spheres = (float4*)((char*)d_ws + F_TOTAL * 16 * 5);        // 512 B

    msdf_prep<<<dim3(1), dim3(1024), 0, stream>>>(verts, faces, pre_n, pre_v, pre_a, spheres);
    msdf_main<<<dim3(P_TOTAL / 2), dim3(TPB), 0, stream>>>(pre_n, pre_v, pre_a, spheres, points, out);
    msdf_loss<<<dim3(1), dim3(256), 0, stream>>>(out);
}

// Round 7
// 89.711 us; speedup vs baseline: 1.1868x; 1.1868x over previous
//
#include <hip/hip_runtime.h>
#include <float.h>

#define P_TOTAL 8192
#define F_TOTAL 2048
#define TPB     256                  // 4 waves: 2 point-pairs x 2 half-scans
#define CHUNK   256
#define HALF_T  (F_TOTAL / 2)        // 1024 tris per wave
#define NCHUNK  (HALF_T / CHUNK)     // 4 chunks per wave

// Correctly-rounded f32 division via shared refined reciprocal (Markstein).
// R8-verified bit-exact on HW.
__device__ __forceinline__ float refine_rcp(float D) {
#pragma clang fp contract(off)
    float r0 = __builtin_amdgcn_rcpf(D);
    float e1 = __builtin_fmaf(-D, r0, 1.0f);
    return __builtin_fmaf(e1, r0, r0);
}
__device__ __forceinline__ float div_rn(float num, float D, float r) {
#pragma clang fp contract(off)
    float q0 = num * r;
    float e  = __builtin_fmaf(-D, q0, num);
    return __builtin_fmaf(e, r, q0);
}

// Scalar region-select, bit-exact vs numpy (proven R2..R17).
__device__ __forceinline__ void region_select(
    float d1, float d2, float d3, float d4, float d5, float d6,
    float va, float vb, float vc, float d43, float d56,
    float g1, float g2, float g3, float g4,
    float& bu, float& bv, float& bw)
{
#pragma clang fp contract(off)
    float G1 = fmaxf(g1, 1e-12f);
    float G2 = fmaxf(g2, 1e-12f);
    float G3 = fmaxf(g3, 1e-12f);
    float G4 = fmaxf(g4, 1e-12f);

    bool cA  = (d1 <= 0.f) & (d2 <= 0.f);
    bool cB  = (d3 >= 0.f) & (d4 <= d3);
    bool cAB = (vc <= 0.f) & (d1 >= 0.f) & (d3 <= 0.f);
    bool cC  = (d6 >= 0.f) & (d5 <= d6);
    bool cAC = (vb <= 0.f) & (d2 >= 0.f) & (d6 <= 0.f);
    bool cBC = (va <= 0.f) & (d43 >= 0.f) & (d56 >= 0.f);

    float nv = cA ? 0.f : cB ? 1.f : cAB ? d1 : cC ? 0.f
             : cAC ? 0.f : cBC ? d43 : vb;
    float nw = cA ? 0.f : cB ? 0.f : cAB ? 0.f : cC ? 1.f
             : cAC ? d2 : cBC ? d43 : vc;
    float D  = cA ? 1.f : cB ? 1.f : cAB ? G1 : cC ? 1.f
             : cAC ? G2 : cBC ? G3 : G4;
    bool fBC = cBC && !(cA || cB || cAB || cC || cAC);

    float r   = refine_rcp(D);
    float qv  = div_rn(nv, D, r);
    float bww = div_rn(nw, D, r);
    float bvv = fBC ? (1.0f - qv) : qv;
    bv = bvv; bw = bww;
    bu = (1.0f - bvv) - bww;
}

// Exact point-vs-tri, R8's verbatim op order (bit-exact vs numpy).
__device__ __forceinline__ float eval_exact(
    float px, float py, float pz, float4 q0, float4 q1, float4 q2)
{
#pragma clang fp contract(off)
    float ax = q0.x, ay = q0.y, az = q0.z;
    float bx = q0.w, by = q1.x, bz = q1.y;
    float cx = q1.z, cy = q1.w, cz = q2.x;

    float abx = bx - ax, aby = by - ay, abz = bz - az;
    float acx = cx - ax, acy = cy - ay, acz = cz - az;
    float apx = px - ax, apy = py - ay, apz = pz - az;
    float d1 = (abx * apx + aby * apy) + abz * apz;
    float d2 = (acx * apx + acy * apy) + acz * apz;
    float bpx = px - bx, bpy = py - by, bpz = pz - bz;
    float d3 = (abx * bpx + aby * bpy) + abz * bpz;
    float d4 = (acx * bpx + acy * bpy) + acz * bpz;
    float cpx = px - cx, cpy = py - cy, cpz = pz - cz;
    float d5 = (abx * cpx + aby * cpy) + abz * cpz;
    float d6 = (acx * cpx + acy * cpy) + acz * cpz;

    float vc = d1 * d4 - d3 * d2;
    float vb = d5 * d2 - d1 * d6;
    float va = d3 * d6 - d5 * d4;
    float d43 = d4 - d3, d56 = d5 - d6;
    float g1 = d1 - d3, g2 = d2 - d6, g3 = d43 + d56, g4 = (va + vb) + vc;

    float bu, bv, bw;
    region_select(d1, d2, d3, d4, d5, d6, va, vb, vc, d43, d56,
                  g1, g2, g3, g4, bu, bv, bw);

    float cpx2 = (ax * bu + bx * bv) + cx * bw;
    float cpy2 = (ay * bu + by * bv) + cy * bw;
    float cpz2 = (az * bu + bz * bv) + cz * bw;
    float dx = px - cpx2, dy = py - cpy2, dz = pz - cpz2;
    return (dx * dx + dy * dy) + dz * dz;
}

// Prep: per-tri plane {n-hat, n-hat.a}, packed verts, A-vertex array.
// R1-proven multi-block version (~2 us). R5 LESSON: a single-block sort
// prep cost +19 us on one CU, and spatial pruning is useless here anyway
// (faces are RANDOM index triples into Gaussian verts -> "triangles" are
// domain-spanning slabs; group spheres never prune).
__global__ __launch_bounds__(256) void msdf_prep(
    const float* __restrict__ verts, const int* __restrict__ faces,
    float4* __restrict__ pre_n, float4* __restrict__ pre_v,
    float4* __restrict__ pre_a)
{
    int t = blockIdx.x * 256 + threadIdx.x;
    int i0 = faces[3 * t + 0], i1 = faces[3 * t + 1], i2 = faces[3 * t + 2];
    float ax = verts[3 * i0], ay = verts[3 * i0 + 1], az = verts[3 * i0 + 2];
    float bx = verts[3 * i1], by = verts[3 * i1 + 1], bz = verts[3 * i1 + 2];
    float cx = verts[3 * i2], cy = verts[3 * i2 + 1], cz = verts[3 * i2 + 2];
    float e1x = bx - ax, e1y = by - ay, e1z = bz - az;
    float e2x = cx - ax, e2y = cy - ay, e2z = cz - az;
    float nx = e1y * e2z - e1z * e2y;
    float ny = e1z * e2x - e1x * e2z;
    float nz = e1x * e2y - e1y * e2x;
    float nn = (nx * nx + ny * ny) + nz * nz;
    float inv = (nn > 1e-30f) ? (1.0f / sqrtf(nn)) : 0.0f;  // degen -> lb=0
    nx *= inv; ny *= inv; nz *= inv;
    pre_n[t] = make_float4(nx, ny, nz, (nx * ax + ny * ay) + nz * az);
    pre_v[3 * t + 0] = make_float4(ax, ay, az, bx);
    pre_v[3 * t + 1] = make_float4(by, bz, cx, cy);
    pre_v[3 * t + 2] = make_float4(cz, 0.f, 0.f, 0.f);
    pre_a[t] = make_float4(ax, ay, az, 0.f);
}

// One eval body over `take` queued survivors of FIFO SL vs point (PX,PY,PZ).
// Dup-head lanes idempotent; accumulates per-lane UBL; caller reduces once
// per flush site (R17 win).
#define FLUSH_BODY(SL, PX, PY, PZ, BB, BI, H, PEND, UBL, take) do {       \
    int j = (lane < (take)) ? lane : 0;                                   \
    int t = slist[SL][((H) + j) & 511];                                   \
    float4 q0 = pre_v[3 * t + 0];                                         \
    float4 q1 = pre_v[3 * t + 1];                                         \
    float4 q2 = pre_v[3 * t + 2];                                         \
    float d2v = eval_exact(PX, PY, PZ, q0, q1, q2);                       \
    unsigned int bits = __float_as_uint(d2v);                             \
    if (bits < (BB)) { (BB) = bits; (BI) = t; }                           \
    (UBL) = fminf((UBL), d2v);                                            \
    (H) += (take); (PEND) -= (take);                                      \
} while (0)

// Branch-and-bound, DUAL-POINT WAVES: wave = (point-pair, half). Each wave
// tests TWO points against ONE pre_n/pre_a load stream -> plane-scan and
// seed global traffic per point HALVED. Theory: main runs at ~35% issue
// efficiency at full occupancy; per-wave reads ~29 KB from a 160 KB
// working set (not L1-resident) -> co-limited by per-CU L1/L2 read
// traffic. Two independent FIFOs per wave (separate ballot/compact/flush
// per point, evals unchanged + bit-exact). No mid-scan barriers (R3
// lesson), no global atomics/fences (R2 lesson: ~150 us).
// Final merge: per point, min of packed (bits,idx) keys from its two
// halves -> first-occurrence argmin preserved (R1-proven semantics).
__global__ __launch_bounds__(TPB) void msdf_main(
    const float4* __restrict__ pre_n, const float4* __restrict__ pre_v,
    const float4* __restrict__ pre_a,
    const float* __restrict__ points, float* __restrict__ out)
{
    __shared__ int slist[8][512];                  // per-wave 2 FIFOs (16 KB)
    __shared__ unsigned long long keys[8];
    const int tid  = threadIdx.x;
    const int lane = tid & 63;
    const int w    = tid >> 6;
    const int pair = w >> 1;                       // 2 point-pairs per block
    const int half = w & 1;
    const int pa   = blockIdx.x * 4 + 2 * pair;    // points pa, pa+1
    const int tb   = half * HALF_T;                // this wave's tri base

    const float pax = points[3 * pa + 0], pay = points[3 * pa + 1], paz = points[3 * pa + 2];
    const float pbx = points[3 * pa + 3], pby = points[3 * pa + 4], pbz = points[3 * pa + 5];

    // ub seeds: A-vertices of this half's first 256 tris, one load stream,
    // two distance accumulations (interleaved shfl reduces for ILP).
    float uA = FLT_MAX, uB = FLT_MAX;
    #pragma unroll
    for (int s = 0; s < 4; ++s) {
        float4 q = pre_a[tb + s * 64 + lane];
        float dax = pax - q.x, day = pay - q.y, daz = paz - q.z;
        uA = fminf(uA, (dax * dax + day * day) + daz * daz);
        float dbx = pbx - q.x, dby = pby - q.y, dbz = pbz - q.z;
        uB = fminf(uB, (dbx * dbx + dby * dby) + dbz * dbz);
    }
    #pragma unroll
    for (int off = 32; off; off >>= 1) {
        uA = fminf(uA, __shfl_xor(uA, off, 64));
        uB = fminf(uB, __shfl_xor(uB, off, 64));
    }
    float ubA = uA, ubB = uB;

    unsigned int bbA = 0xFFFFFFFFu, bbB = 0xFFFFFFFFu;
    int biA = 0, biB = 0;
    int pendA = 0, hA = 0, pendB = 0, hB = 0;

    for (int c = 0; c < NCHUNK; ++c) {
        const float ubmA = ubA * 1.02f + 1e-18f;
        const float ubmB = ubB * 1.02f + 1e-18f;
        #pragma unroll
        for (int s = 0; s < 4; ++s) {
            int t = tb + c * CHUNK + s * 64 + lane;
            float4 n = pre_n[t];
            float lvA = ((n.x * pax + n.y * pay) + n.z * paz) - n.w;
            float lvB = ((n.x * pbx + n.y * pby) + n.z * pbz) - n.w;
            bool prA = (lvA * lvA <= ubmA);
            bool prB = (lvB * lvB <= ubmB);
            unsigned long long mA = __ballot(prA);
            unsigned long long mB = __ballot(prB);
            if (prA) {
                int off = (int)__popcll(mA & ((1ull << lane) - 1ull));
                slist[2 * w + 0][(hA + pendA + off) & 511] = t;
            }
            pendA += (int)__popcll(mA);
            if (prB) {
                int off = (int)__popcll(mB & ((1ull << lane) - 1ull));
                slist[2 * w + 1][(hB + pendB + off) & 511] = t;
            }
            pendB += (int)__popcll(mB);
        }

        bool drain = (c == 0) || (c == NCHUNK - 1);
        if (pendA >= 64 || (drain && pendA > 0)) {
            float ubloc = FLT_MAX;
            while (pendA >= 64)
                FLUSH_BODY(2 * w + 0, pax, pay, paz, bbA, biA, hA, pendA, ubloc, 64);
            if (drain && pendA > 0)
                FLUSH_BODY(2 * w + 0, pax, pay, paz, bbA, biA, hA, pendA, ubloc, pendA);
            #pragma unroll
            for (int off = 32; off; off >>= 1)
                ubloc = fminf(ubloc, __shfl_xor(ubloc, off, 64));
            ubA = fminf(ubA, ubloc);
        }
        if (pendB >= 64 || (drain && pendB > 0)) {
            float ubloc = FLT_MAX;
            while (pendB >= 64)
                FLUSH_BODY(2 * w + 1, pbx, pby, pbz, bbB, biB, hB, pendB, ubloc, 64);
            if (drain && pendB > 0)
                FLUSH_BODY(2 * w + 1, pbx, pby, pbz, bbB, biB, hB, pendB, ubloc, pendB);
            #pragma unroll
            for (int off = 32; off; off >>= 1)
                ubloc = fminf(ubloc, __shfl_xor(ubloc, off, 64));
            ubB = fminf(ubB, ubloc);
        }
    }

    // in-wave packed mins (interleaved), then cross-half merge per point
    unsigned long long keyA =
        ((unsigned long long)bbA << 32) | (unsigned int)biA;
    unsigned long long keyB =
        ((unsigned long long)bbB << 32) | (unsigned int)biB;
    #pragma unroll
    for (int off = 32; off > 0; off >>= 1) {
        unsigned int hiA = (unsigned int)(keyA >> 32);
        unsigned int loA = (unsigned int)(keyA & 0xFFFFFFFFu);
        unsigned int ohiA = __shfl_down(hiA, off, 64);
        unsigned int oloA = __shfl_down(loA, off, 64);
        unsigned long long okA = ((unsigned long long)ohiA << 32) | oloA;
        keyA = (okA < keyA) ? okA : keyA;
        unsigned int hiB = (unsigned int)(keyB >> 32);
        unsigned int loB = (unsigned int)(keyB & 0xFFFFFFFFu);
        unsigned int ohiB = __shfl_down(hiB, off, 64);
        unsigned int oloB = __shfl_down(loB, off, 64);
        unsigned long long okB = ((unsigned long long)ohiB << 32) | oloB;
        keyB = (okB < keyB) ? okB : keyB;
    }
    if (lane == 0) { keys[2 * w + 0] = keyA; keys[2 * w + 1] = keyB; }
    __syncthreads();
    if (tid < 4) {                                 // tid = 2*pair + j
        int pr = tid >> 1, j = tid & 1;
        unsigned long long k0 = keys[2 * (2 * pr + 0) + j];   // half 0
        unsigned long long k1 = keys[2 * (2 * pr + 1) + j];   // half 1
        unsigned long long km = (k1 < k0) ? k1 : k0;
        int pp = blockIdx.x * 4 + 2 * pr + j;
        out[1 + pp]           = __uint_as_float((unsigned int)(km >> 32));
        out[1 + P_TOTAL + pp] = (float)(unsigned int)(km & 0xFFFFFFFFu);
    }
}

// Deterministic single-block loss reduction: out[0] = sum(dist) * 1000/P.
// No atomics (R5 lesson; re-confirmed catastrophically in R2 — contended
// device atomics + fences cost ~150 us).
__global__ __launch_bounds__(256) void msdf_loss(float* __restrict__ out)
{
    __shared__ float wsum[4];
    float s = 0.f;
    for (int k = 0; k < P_TOTAL / 256; ++k)
        s += out[1 + k * 256 + threadIdx.x];
    #pragma unroll
    for (int off = 32; off > 0; off >>= 1) s += __shfl_down(s, off, 64);
    int lane = threadIdx.x & 63, w = threadIdx.x >> 6;
    if (lane == 0) wsum[w] = s;
    __syncthreads();
    if (threadIdx.x == 0) {
        float tot = ((wsum[0] + wsum[1]) + wsum[2]) + wsum[3];
        out[0] = tot * (1000.0f / (float)P_TOTAL);
    }
}

extern "C" void kernel_launch(void* const* d_in, const int* in_sizes, int n_in,
                              void* d_out, int out_size, void* d_ws, size_t ws_size,
                              hipStream_t stream) {
    const float* verts  = (const float*)d_in[0];
    const int*   faces  = (const int*)d_in[1];
    const float* points = (const float*)d_in[2];
    float* out = (float*)d_out;
    float4* pre_n = (float4*)d_ws;                                      // 32 KB
    float4* pre_v = (float4*)((char*)d_ws + F_TOTAL * 16);              // 96 KB
    float4* pre_a = (float4*)((char*)d_ws + F_TOTAL * 16 * 4);          // 32 KB

    msdf_prep<<<dim3(F_TOTAL / 256), dim3(256), 0, stream>>>(verts, faces, pre_n, pre_v, pre_a);
    msdf_main<<<dim3(P_TOTAL / 4), dim3(TPB), 0, stream>>>(pre_n, pre_v, pre_a, points, out);
    msdf_loss<<<dim3(1), dim3(256), 0, stream>>>(out);
}

// Round 10
// 88.971 us; speedup vs baseline: 1.1967x; 1.0083x over previous
//
#include <hip/hip_runtime.h>
#include <float.h>

#define P_TOTAL 8192
#define F_TOTAL 2048
#define TPB     256                  // 4 waves: 2 points x 2 half-scans
#define CHUNK   256
#define HALF_T  (F_TOTAL / 2)        // 1024 tris per wave
#define NCHUNK  (HALF_T / CHUNK)     // 4 chunks per wave

// Correctly-rounded f32 division via shared refined reciprocal (Markstein).
// R8-verified bit-exact on HW.
__device__ __forceinline__ float refine_rcp(float D) {
#pragma clang fp contract(off)
    float r0 = __builtin_amdgcn_rcpf(D);
    float e1 = __builtin_fmaf(-D, r0, 1.0f);
    return __builtin_fmaf(e1, r0, r0);
}
__device__ __forceinline__ float div_rn(float num, float D, float r) {
#pragma clang fp contract(off)
    float q0 = num * r;
    float e  = __builtin_fmaf(-D, q0, num);
    return __builtin_fmaf(e, r, q0);
}

// Prune threshold: relative slack + absolute fp slack. The sqrt term
// covers 2*lv*delta (delta <= ~1e-5 for non-sliver tris, see prep) with
// 2x headroom; 1e-9 floor covers delta^2 as ub->0. Strictly wider than
// R1's proven ub*1.02+1e-18 -> safe direction.
__device__ __forceinline__ float prune_ubm(float ub, float rel) {
    return ub * rel + 4e-5f * sqrtf(ub) + 1e-9f;
}

// Scalar region-select, bit-exact vs numpy (proven R2..R17).
__device__ __forceinline__ void region_select(
    float d1, float d2, float d3, float d4, float d5, float d6,
    float va, float vb, float vc, float d43, float d56,
    float g1, float g2, float g3, float g4,
    float& bu, float& bv, float& bw)
{
#pragma clang fp contract(off)
    float G1 = fmaxf(g1, 1e-12f);
    float G2 = fmaxf(g2, 1e-12f);
    float G3 = fmaxf(g3, 1e-12f);
    float G4 = fmaxf(g4, 1e-12f);

    bool cA  = (d1 <= 0.f) & (d2 <= 0.f);
    bool cB  = (d3 >= 0.f) & (d4 <= d3);
    bool cAB = (vc <= 0.f) & (d1 >= 0.f) & (d3 <= 0.f);
    bool cC  = (d6 >= 0.f) & (d5 <= d6);
    bool cAC = (vb <= 0.f) & (d2 >= 0.f) & (d6 <= 0.f);
    bool cBC = (va <= 0.f) & (d43 >= 0.f) & (d56 >= 0.f);

    float nv = cA ? 0.f : cB ? 1.f : cAB ? d1 : cC ? 0.f
             : cAC ? 0.f : cBC ? d43 : vb;
    float nw = cA ? 0.f : cB ? 0.f : cAB ? 0.f : cC ? 1.f
             : cAC ? d2 : cBC ? d43 : vc;
    float D  = cA ? 1.f : cB ? 1.f : cAB ? G1 : cC ? 1.f
             : cAC ? G2 : cBC ? G3 : G4;
    bool fBC = cBC && !(cA || cB || cAB || cC || cAC);

    float r   = refine_rcp(D);
    float qv  = div_rn(nv, D, r);
    float bww = div_rn(nw, D, r);
    float bvv = fBC ? (1.0f - qv) : qv;
    bv = bvv; bw = bww;
    bu = (1.0f - bvv) - bww;
}

// Exact point-vs-tri, R8's verbatim op order (bit-exact vs numpy).
__device__ __forceinline__ float eval_exact(
    float px, float py, float pz, float4 q0, float4 q1, float4 q2)
{
#pragma clang fp contract(off)
    float ax = q0.x, ay = q0.y, az = q0.z;
    float bx = q0.w, by = q1.x, bz = q1.y;
    float cx = q1.z, cy = q1.w, cz = q2.x;

    float abx = bx - ax, aby = by - ay, abz = bz - az;
    float acx = cx - ax, acy = cy - ay, acz = cz - az;
    float apx = px - ax, apy = py - ay, apz = pz - az;
    float d1 = (abx * apx + aby * apy) + abz * apz;
    float d2 = (acx * apx + acy * apy) + acz * apz;
    float bpx = px - bx, bpy = py - by, bpz = pz - bz;
    float d3 = (abx * bpx + aby * bpy) + abz * bpz;
    float d4 = (acx * bpx + acy * bpy) + acz * bpz;
    float cpx = px - cx, cpy = py - cy, cpz = pz - cz;
    float d5 = (abx * cpx + aby * cpy) + abz * cpz;
    float d6 = (acx * cpx + acy * cpy) + acz * cpz;

    float vc = d1 * d4 - d3 * d2;
    float vb = d5 * d2 - d1 * d6;
    float va = d3 * d6 - d5 * d4;
    float d43 = d4 - d3, d56 = d5 - d6;
    float g1 = d1 - d3, g2 = d2 - d6, g3 = d43 + d56, g4 = (va + vb) + vc;

    float bu, bv, bw;
    region_select(d1, d2, d3, d4, d5, d6, va, vb, vc, d43, d56,
                  g1, g2, g3, g4, bu, bv, bw);

    float cpx2 = (ax * bu + bx * bv) + cx * bw;
    float cpy2 = (ay * bu + by * bv) + cy * bw;
    float cpz2 = (az * bu + bz * bv) + cz * bw;
    float dx = px - cpx2, dy = py - cpy2, dz = pz - cpz2;
    return (dx * dx + dy * dy) + dz * dz;
}

// Prep: per-tri plane {n-hat, n-hat.a}, packed verts, A-vertex array.
// R9 ERRATA (root cause of R8/R9 identical assoc failures): the plane
// lower bound lv^2 <= d2 is UNSOUND in fp for NEAR-DEGENERATE (sliver)
// triangles. faces are random index triples -> some tris are nearly
// collinear; |e1 x e2| is then dominated by ~1e-6 fp noise and the
// normalized n-hat points in a RANDOM direction, so lv can be O(1) while
// the true distance is small. R1 survived only because its loose chunk-0
// seed threshold exceeded the noise for the one fragile (point, sliver)
// pair; any tightening (R8/R9 early drain) deterministically pruned the
// true argmin (dist passed -- a tie partner survived -- assoc off by 577,
// identical under both margins). FIX: flag slivers (sin theta < 0.1,
// i.e. nn <= 1e-2*|e1|^2*|e2|^2) -> n-hat = 0 -> lv = 0 -> never pruned,
// always evaluated exactly. ~0.25% of random tris -> ~5 extra evals,
// negligible. Non-flagged tris have n-hat direction error <= ~1.2e-6 ->
// lv abs error <= ~1e-5, covered by prune_ubm's 4e-5*sqrt(ub) term.
__global__ __launch_bounds__(256) void msdf_prep(
    const float* __restrict__ verts, const int* __restrict__ faces,
    float4* __restrict__ pre_n, float4* __restrict__ pre_v,
    float4* __restrict__ pre_a)
{
    int t = blockIdx.x * 256 + threadIdx.x;
    int i0 = faces[3 * t + 0], i1 = faces[3 * t + 1], i2 = faces[3 * t + 2];
    float ax = verts[3 * i0], ay = verts[3 * i0 + 1], az = verts[3 * i0 + 2];
    float bx = verts[3 * i1], by = verts[3 * i1 + 1], bz = verts[3 * i1 + 2];
    float cx = verts[3 * i2], cy = verts[3 * i2 + 1], cz = verts[3 * i2 + 2];
    float e1x = bx - ax, e1y = by - ay, e1z = bz - az;
    float e2x = cx - ax, e2y = cy - ay, e2z = cz - az;
    float nx = e1y * e2z - e1z * e2y;
    float ny = e1z * e2x - e1x * e2z;
    float nz = e1x * e2y - e1y * e2x;
    float nn = (nx * nx + ny * ny) + nz * nz;
    float e1sq = (e1x * e1x + e1y * e1y) + e1z * e1z;
    float e2sq = (e2x * e2x + e2y * e2y) + e2z * e2z;
    // sliver/degenerate guard: sin^2(theta) = nn/(e1sq*e2sq) must exceed
    // 1e-2 for the plane lb to be numerically sound; else lb = 0.
    float inv = (nn > 1e-2f * (e1sq * e2sq)) ? (1.0f / sqrtf(nn)) : 0.0f;
    nx *= inv; ny *= inv; nz *= inv;
    pre_n[t] = make_float4(nx, ny, nz, (nx * ax + ny * ay) + nz * az);
    pre_v[3 * t + 0] = make_float4(ax, ay, az, bx);
    pre_v[3 * t + 1] = make_float4(by, bz, cx, cy);
    pre_v[3 * t + 2] = make_float4(cz, 0.f, 0.f, 0.f);
    pre_a[t] = make_float4(ax, ay, az, 0.f);
}

// One eval body over `take` queued survivors (dup-head lanes idempotent).
// Accumulates per-lane ubloc; caller reduces once per flush site (R17 win).
#define FLUSH_BODY(take) do {                                             \
    int j = (lane < (take)) ? lane : 0;                                   \
    int t = slist[w][(h + j) & 511];                                      \
    float4 q0 = pre_v[3 * t + 0];                                         \
    float4 q1 = pre_v[3 * t + 1];                                         \
    float4 q2 = pre_v[3 * t + 2];                                         \
    float d2v = eval_exact(px, py, pz, q0, q1, q2);                       \
    unsigned int bits = __float_as_uint(d2v);                             \
    if (bits < best_bits) { best_bits = bits; best_idx = t; }             \
    ubloc = fminf(ubloc, d2v);                                            \
    h += (take); pend -= (take);                                          \
} while (0)

// One 64-tri plane-test round at tri base T vs margin UBM.
#define SCAN_ROUND(T, UBM) do {                                           \
    int t = (T);                                                          \
    float4 n = pre_n[t];                                                  \
    float lv = ((n.x * px + n.y * py) + n.z * pz) - n.w;                  \
    bool pred = (lv * lv <= (UBM));                                       \
    unsigned long long m = __ballot(pred);                                \
    if (pred) {                                                           \
        int off = (int)__popcll(m & ((1ull << lane) - 1ull));             \
        slist[w][(h + pend + off) & 511] = t;                             \
    }                                                                     \
    pend += (int)__popcll(m);                                             \
} while (0)

// Full drain of the pending FIFO + cross-lane ub collapse.
#define DRAIN_AND_REDUCE() do {                                           \
    float ubloc = FLT_MAX;                                                \
    while (pend >= 64) FLUSH_BODY(64);                                    \
    if (pend > 0) FLUSH_BODY(pend);                                       \
    _Pragma("unroll")                                                     \
    for (int off = 32; off; off >>= 1)                                    \
        ubloc = fminf(ubloc, __shfl_xor(ubloc, off, 64));                 \
    ub = fminf(ub, ubloc);                                                \
} while (0)

// Branch-and-bound, 2 WAVES PER POINT (R1-proven wave structure) with the
// EARLY 64-TRI DRAIN (flush after chunk 0's first round; the collapsed ub
// then prunes rounds 1-3 and chunks 1-3 tightly -> ~2x fewer scattered
// pre_v gather evals, the diagnosed dominant cost). Soundness now rests on
// the sliver fix in prep (see its comment): flagged tris have lb=0 and are
// always evaluated; non-flagged tris' fp error is covered by prune_ubm's
// additive slack. Argmin + all exact-tie partners always survive
// (lv^2 <= d2min <= ub <= ubm) -> FIFO stays ascending-t, strict-less
// best + cross-wave min-key -> first-occurrence argmin preserved.
// R2 LESSON: no contended global atomics/fences (~150 us).
// R3 LESSON: no mid-scan cross-wave __syncthreads.
__global__ __launch_bounds__(TPB) void msdf_main(
    const float4* __restrict__ pre_n, const float4* __restrict__ pre_v,
    const float4* __restrict__ pre_a,
    const float* __restrict__ points, float* __restrict__ out)
{
    __shared__ int slist[4][512];                  // per-wave FIFO (8 KB)
    __shared__ unsigned long long keys[4];
    const int tid  = threadIdx.x;
    const int lane = tid & 63;
    const int w    = tid >> 6;
    const int p    = blockIdx.x * 2 + (w >> 1);    // 2 points per block
    const int tb   = (w & 1) * HALF_T;             // this wave's tri base

    const float px = points[3 * p], py = points[3 * p + 1], pz = points[3 * p + 2];

    // ub seed: A-vertices of this half's first 256 tris (actual mesh points)
    float u = FLT_MAX;
    #pragma unroll
    for (int s = 0; s < 4; ++s) {
        float4 q = pre_a[tb + s * 64 + lane];
        float dx = px - q.x, dy = py - q.y, dz = pz - q.z;
        u = fminf(u, (dx * dx + dy * dy) + dz * dz);
    }
    #pragma unroll
    for (int off = 32; off; off >>= 1)
        u = fminf(u, __shfl_xor(u, off, 64));
    float ub = u;

    unsigned int best_bits = 0xFFFFFFFFu;
    int best_idx = 0;
    int pend = 0, h = 0;

    // ---- chunk 0: round 0 at the seed threshold -> EARLY drain
    // (collapses ub to near-final), then rounds 1-3 at the collapsed
    // threshold (extra rel headroom), then drain.
    {
        const float ubm0 = prune_ubm(ub, 1.02f);
        SCAN_ROUND(tb + lane, ubm0);
        if (pend > 0) DRAIN_AND_REDUCE();

        const float ubm1 = prune_ubm(ub, 1.05f);
        #pragma unroll
        for (int s = 1; s < 4; ++s)
            SCAN_ROUND(tb + s * 64 + lane, ubm1);
        if (pend > 0) DRAIN_AND_REDUCE();
    }

    // ---- chunks 1..3: R1 flush policy, hardened threshold.
    for (int c = 1; c < NCHUNK; ++c) {
        const float ubm = prune_ubm(ub, 1.02f);
        #pragma unroll
        for (int s = 0; s < 4; ++s)
            SCAN_ROUND(tb + c * CHUNK + s * 64 + lane, ubm);

        bool drain = (c == NCHUNK - 1);
        if (pend >= 64 || (drain && pend > 0)) {
            float ubloc = FLT_MAX;
            while (pend >= 64) FLUSH_BODY(64);
            if (drain && pend > 0) FLUSH_BODY(pend);
            #pragma unroll
            for (int off = 32; off; off >>= 1)
                ubloc = fminf(ubloc, __shfl_xor(ubloc, off, 64));
            ub = fminf(ub, ubloc);
        }
    }

    // in-wave packed min, then cross-wave merge of the two halves
    unsigned long long key =
        ((unsigned long long)best_bits << 32) | (unsigned int)best_idx;
    #pragma unroll
    for (int off = 32; off > 0; off >>= 1) {
        unsigned int hi = (unsigned int)(key >> 32);
        unsigned int lo = (unsigned int)(key & 0xFFFFFFFFu);
        unsigned int ohi = __shfl_down(hi, off, 64);
        unsigned int olo = __shfl_down(lo, off, 64);
        unsigned long long ok = ((unsigned long long)ohi << 32) | olo;
        key = (ok < key) ? ok : key;
    }
    if (lane == 0) keys[w] = key;
    __syncthreads();
    if (tid < 2) {                                  // tid: point blockIdx*2+tid
        unsigned long long k0 = keys[2 * tid];
        unsigned long long k1 = keys[2 * tid + 1];
        unsigned long long km = (k1 < k0) ? k1 : k0;
        int pp = blockIdx.x * 2 + tid;
        out[1 + pp]           = __uint_as_float((unsigned int)(km >> 32));
        out[1 + P_TOTAL + pp] = (float)(unsigned int)(km & 0xFFFFFFFFu);
    }
}

// Deterministic single-block loss reduction: out[0] = sum(dist) * 1000/P.
// No atomics (R5 lesson; re-confirmed catastrophically in R2 — contended
// device atomics + fences cost ~150 us).
__global__ __launch_bounds__(256) void msdf_loss(float* __restrict__ out)
{
    __shared__ float wsum[4];
    float s = 0.f;
    for (int k = 0; k < P_TOTAL / 256; ++k)
        s += out[1 + k * 256 + threadIdx.x];
    #pragma unroll
    for (int off = 32; off > 0; off >>= 1) s += __shfl_down(s, off, 64);
    int lane = threadIdx.x & 63, w = threadIdx.x >> 6;
    if (lane == 0) wsum[w] = s;
    __syncthreads();
    if (threadIdx.x == 0) {
        float tot = ((wsum[0] + wsum[1]) + wsum[2]) + wsum[3];
        out[0] = tot * (1000.0f / (float)P_TOTAL);
    }
}

extern "C" void kernel_launch(void* const* d_in, const int* in_sizes, int n_in,
                              void* d_out, int out_size, void* d_ws, size_t ws_size,
                              hipStream_t stream) {
    const float* verts  = (const float*)d_in[0];
    const int*   faces  = (const int*)d_in[1];
    const float* points = (const float*)d_in[2];
    float* out = (float*)d_out;
    float4* pre_n = (float4*)d_ws;                                      // 32 KB
    float4* pre_v = (float4*)((char*)d_ws + F_TOTAL * 16);              // 96 KB
    float4* pre_a = (float4*)((char*)d_ws + F_TOTAL * 16 * 4);          // 32 KB

    msdf_prep<<<dim3(F_TOTAL / 256), dim3(256), 0, stream>>>(verts, faces, pre_n, pre_v, pre_a);
    msdf_main<<<dim3(P_TOTAL / 2), dim3(TPB), 0, stream>>>(pre_n, pre_v, pre_a, points, out);
    msdf_loss<<<dim3(1), dim3(256), 0, stream>>>(out);
}